// Round 6
// baseline (458.009 us; speedup 1.0000x reference)
//
#include <hip/hip_runtime.h>
#include <cstdint>

typedef unsigned long long u64;

#define THRESH 0.5f
#define SIGMA 2.0f
#define TPB 64      // pair-tile dim (64x64 pairs per tile)
#define NSPLIT 16   // K splits per tile (1024 words / 16 = 64-word chunks)
#define CST 66      // LDS row stride (u64): <=2-way bank aliasing (free)
#define MAXN 512    // tail capacity (N=500)
#define CAP 16      // per-row cached suppressor list (mean ~3, overflow -> rescan)

struct TailShared {
    u64 key[MAXN];               // (score_bits<<32)|(~idx): key[a]>key[b] <=> a sorts before b
    float score[MAXN];
    float sum[MAXN];
    int label[MAXN];
    float comp[MAXN];
    unsigned short cnt[MAXN];
    unsigned short rank[MAXN];
    unsigned short alist[MAXN][CAP];
    float dlist[MAXN][CAP];
    int isLast;
};                               // ~63.5 KB

union InterShared {
    u64 sm[2 * TPB][CST];        // 67,584 B staging for the popcount phase
    TailShared t;                // reused by the last-block tail
};

// ---------------------------------------------------------------------------
// K1: 4 blocks per mask. Binarize + bit-pack via 64-lane __ballot (fixed
// pixel<->bit bijection, identical for all masks -> popcount(AND) exact),
// 4-deep float4 load pipeline, fp64 partial soft-sums. Also zero-fills
// interFull (1 MB spread over 2000 blocks) and the done counter, so K2
// needs no memset node.
// ---------------------------------------------------------------------------
__global__ __launch_bounds__(256) void k_pack(
    const float* __restrict__ preds, u64* __restrict__ packed,
    double* __restrict__ pssum, int* __restrict__ pcnt,
    unsigned* __restrict__ interFull, unsigned* __restrict__ doneCnt,
    int N, int HW)
{
    const int task = blockIdx.x;
    const int i = task >> 2, sub = task & 3;
    const int seg = HW >> 2;
    const float* src = preds + (size_t)i * HW + (size_t)sub * seg;
    u64* dst = packed + (size_t)i * (HW >> 6) + (size_t)sub * (seg >> 6);
    const int tid = threadIdx.x;
    const int wave = tid >> 6, lane = tid & 63;

    // zero-init slice of interFull + done counter (coherent via kernel boundary)
    {
        const size_t NN = (size_t)N * N;
        const size_t zbase = (size_t)task * 128;
        for (int z = tid; z < 128; z += 256) {
            const size_t idx = zbase + (size_t)z;
            if (idx < NN) interFull[idx] = 0u;
        }
        if (task == 0 && tid == 0) *doneCnt = 0u;
    }

    double ssum = 0.0;
    int cnt = 0;
    const int iters = seg >> 12;                  // 4096 px per block-iter
    for (int k = 0; k < iters; ++k) {
        const int base = (k << 12) + (wave << 10) + (lane << 2);
        const float4 v0 = *reinterpret_cast<const float4*>(src + base);
        const float4 v1 = *reinterpret_cast<const float4*>(src + base + 256);
        const float4 v2 = *reinterpret_cast<const float4*>(src + base + 512);
        const float4 v3 = *reinterpret_cast<const float4*>(src + base + 768);
        #pragma unroll
        for (int q = 0; q < 4; ++q) {
            const float4 v = (q == 0) ? v0 : (q == 1) ? v1 : (q == 2) ? v2 : v3;
            const bool b0 = v.x > THRESH, b1 = v.y > THRESH, b2 = v.z > THRESH, b3 = v.w > THRESH;
            const u64 m0 = __ballot(b0);
            const u64 m1 = __ballot(b1);
            const u64 m2 = __ballot(b2);
            const u64 m3 = __ballot(b3);
            if (lane < 4) {
                const u64 m = (lane == 0) ? m0 : (lane == 1) ? m1 : (lane == 2) ? m2 : m3;
                dst[(k << 6) + (wave << 4) + (q << 2) + lane] = m;
            }
            cnt += (int)b0 + (int)b1 + (int)b2 + (int)b3;
            ssum += (b0 ? (double)v.x : 0.0) + (b1 ? (double)v.y : 0.0)
                  + (b2 ? (double)v.z : 0.0) + (b3 ? (double)v.w : 0.0);
        }
    }
    for (int off = 32; off > 0; off >>= 1) {
        ssum += __shfl_down(ssum, off);
        cnt  += __shfl_down(cnt, off);
    }
    __shared__ double ls[4];
    __shared__ int lc[4];
    if (lane == 0) { ls[wave] = ssum; lc[wave] = cnt; }
    __syncthreads();
    if (tid == 0) {
        pssum[task] = ls[0] + ls[1] + ls[2] + ls[3];
        pcnt[task]  = lc[0] + lc[1] + lc[2] + lc[3];
    }
}

// ---------------------------------------------------------------------------
// K2: pairwise intersections (unsorted pairs; sort applied logically via the
// key downstream) + LAST-BLOCK TAIL doing comp/rank/final in one block.
// Grid (ntri, NSPLIT); 16x16 threads, 4x4 register sub-tiles; per-split
// partial counts atomicAdd'ed (device scope) into dense interFull.
// Last block: release/acquire via doneCnt, then the whole matrix-NMS tail
// with scores/keys/labels in LDS; interFull read with device-scope loads.
// ---------------------------------------------------------------------------
__global__ __launch_bounds__(256) void k_inter(
    const u64* __restrict__ packed, unsigned* __restrict__ interFull,
    unsigned* __restrict__ doneCnt,
    const double* __restrict__ pssum, const int* __restrict__ pcnt,
    const float* __restrict__ cate, const int* __restrict__ labels,
    float* __restrict__ out, int N, int WORDS, int NT)
{
    __shared__ InterShared sh;
    __shared__ float gred[4];
    const int tid = threadIdx.x;
    const int wave = tid >> 6, lane = tid & 63;

    // ---- popcount phase ----
    {
        int b = blockIdx.x;
        int ti = 0, rowlen = NT;
        while (b >= rowlen) { b -= rowlen; ++ti; --rowlen; }
        const int tj = ti + b;
        const int kwords = WORDS / NSPLIT;
        const int kbase = blockIdx.y * kwords;
        const int a = tid >> 4, bb = tid & 15;

        const int half = kwords >> 1;
        for (int idx = tid; idx < 2 * TPB * half; idx += 256) {
            const int ml = idx / half;
            const int w = (idx - ml * half) << 1;
            const int g = (ml < TPB) ? (ti * TPB + ml) : (tj * TPB + (ml - TPB));
            u64 x0 = 0, x1 = 0;
            if (g < N) {
                const u64* p = packed + (size_t)g * WORDS + kbase + w;
                x0 = p[0];
                x1 = p[1];
            }
            sh.sm[ml][w] = x0;
            sh.sm[ml][w + 1] = x1;
        }
        __syncthreads();

        unsigned acc[4][4] = {};
        #pragma unroll 4
        for (int w = 0; w < kwords; w += 2) {
            u64 pi0[4], pi1[4], pj0[4], pj1[4];
            #pragma unroll
            for (int t = 0; t < 4; ++t) {
                const ulonglong2 q = *reinterpret_cast<const ulonglong2*>(&sh.sm[4 * a + t][w]);
                pi0[t] = q.x; pi1[t] = q.y;
            }
            #pragma unroll
            for (int s = 0; s < 4; ++s) {
                const ulonglong2 q = *reinterpret_cast<const ulonglong2*>(&sh.sm[TPB + bb + 16 * s][w]);
                pj0[s] = q.x; pj1[s] = q.y;
            }
            #pragma unroll
            for (int t = 0; t < 4; ++t)
                #pragma unroll
                for (int s = 0; s < 4; ++s)
                    acc[t][s] += (unsigned)__popcll(pi0[t] & pj0[s])
                               + (unsigned)__popcll(pi1[t] & pj1[s]);
        }
        #pragma unroll
        for (int t = 0; t < 4; ++t)
            #pragma unroll
            for (int s = 0; s < 4; ++s) {
                const int gi = ti * TPB + 4 * a + t;
                const int gj = tj * TPB + bb + 16 * s;
                if (gj < N && gi < gj)
                    atomicAdd(&interFull[(size_t)gi * N + gj], acc[t][s]);
            }
    }

    // ---- last-block election (release/acquire over doneCnt) ----
    __syncthreads();                      // all sm reads done before union reuse
    if (tid == 0) {
        __threadfence();                  // release: my atomics visible before counter bump
        const unsigned total = gridDim.x * gridDim.y;
        const unsigned prev = atomicAdd(doneCnt, 1u);
        sh.t.isLast = (prev == total - 1u) ? 1 : 0;
    }
    __syncthreads();
    if (!sh.t.isLast) return;
    __threadfence();                      // acquire: see all blocks' atomics

    // ---- tail: finalize scores, comp, rank, final decay ----
    for (int b = tid; b < N; b += 256) {
        const double S = ((pssum[4*b] + pssum[4*b+1]) + pssum[4*b+2]) + pssum[4*b+3];
        const int C = ((pcnt[4*b] + pcnt[4*b+1]) + pcnt[4*b+2]) + pcnt[4*b+3];
        const float sc = cate[b] * (float)(S / (double)(C > 1 ? C : 1));
        sh.t.score[b] = sc;
        sh.t.sum[b] = (float)C;
        sh.t.label[b] = labels[b];
        sh.t.key[b] = ((u64)__float_as_uint(sc) << 32) | (u64)(0xFFFFFFFFu - (unsigned)b);
    }
    __syncthreads();

    // Phase A: comp[b] = max iou over suppressors; rank(b); cache suppressor list
    for (int b = tid; b < N; b += 256) {
        const u64 kb = sh.t.key[b];
        const int lb = sh.t.label[b];
        const float sub = sh.t.sum[b];
        float cmax = 0.0f;
        int r = 0, c = 0;
        for (int a2 = 0; a2 < N; ++a2) {
            if (sh.t.key[a2] > kb) {
                ++r;
                if (sh.t.label[a2] == lb) {
                    const int lo = a2 < b ? a2 : b, hi = a2 < b ? b : a2;
                    const unsigned iv = __hip_atomic_load(
                        &interFull[(size_t)lo * N + hi],
                        __ATOMIC_RELAXED, __HIP_MEMORY_SCOPE_AGENT);
                    const float inter = (float)iv;
                    const float un = sh.t.sum[a2] + sub - inter;
                    const float d = inter / fmaxf(un, 1.0f);
                    cmax = fmaxf(cmax, d);
                    if (c < CAP) { sh.t.alist[b][c] = (unsigned short)a2; sh.t.dlist[b][c] = d; }
                    ++c;
                }
            }
        }
        sh.t.comp[b] = cmax;
        sh.t.rank[b] = (unsigned short)r;
        sh.t.cnt[b] = (unsigned short)c;
    }
    __syncthreads();

    // global min of comp (covers all d=0 contributions: max_a(-comp[a]^2) = -gmin^2)
    float gm = 3.0e38f;
    for (int b = tid; b < N; b += 256) gm = fminf(gm, sh.t.comp[b]);
    for (int off = 32; off > 0; off >>= 1) gm = fminf(gm, __shfl_down(gm, off));
    if (lane == 0) gred[wave] = gm;
    __syncthreads();
    const float gmin = fminf(fminf(gred[0], gred[1]), fminf(gred[2], gred[3]));

    // Phase B: m[b] = max(-gmin^2, max over suppressors (d^2 - comp[a]^2))
    for (int b = tid; b < N; b += 256) {
        float m = -(gmin * gmin);
        const int c = sh.t.cnt[b];
        if (c <= CAP) {
            for (int k2 = 0; k2 < c; ++k2) {
                const int a2 = sh.t.alist[b][k2];
                const float d = sh.t.dlist[b][k2];
                const float ca = sh.t.comp[a2];
                m = fmaxf(m, d * d - ca * ca);
            }
        } else {  // overflow fallback (never expected with random labels)
            const u64 kb = sh.t.key[b];
            const int lb = sh.t.label[b];
            const float sub = sh.t.sum[b];
            for (int a2 = 0; a2 < N; ++a2) {
                if (sh.t.key[a2] > kb && sh.t.label[a2] == lb) {
                    const int lo = a2 < b ? a2 : b, hi = a2 < b ? b : a2;
                    const unsigned iv = __hip_atomic_load(
                        &interFull[(size_t)lo * N + hi],
                        __ATOMIC_RELAXED, __HIP_MEMORY_SCOPE_AGENT);
                    const float inter = (float)iv;
                    const float un = sh.t.sum[a2] + sub - inter;
                    const float d = inter / fmaxf(un, 1.0f);
                    const float ca = sh.t.comp[a2];
                    m = fmaxf(m, d * d - ca * ca);
                }
            }
        }
        out[sh.t.rank[b]] = sh.t.score[b] * expf(-SIGMA * m);
    }
}

extern "C" void kernel_launch(void* const* d_in, const int* in_sizes, int n_in,
                              void* d_out, int out_size, void* d_ws, size_t ws_size,
                              hipStream_t stream)
{
    const float* preds  = (const float*)d_in[0];
    const float* cate   = (const float*)d_in[1];
    const int*   labels = (const int*)d_in[2];
    float* out = (float*)d_out;

    const int N = in_sizes[1];
    const int HW = in_sizes[0] / N;
    const int WORDS = HW >> 6;

    char* ws = (char*)d_ws;
    size_t off = 0;
    auto take = [&](size_t bytes) -> void* {
        void* p = ws + off;
        off = (off + bytes + 255) & ~(size_t)255;
        return p;
    };
    u64*      packed   = (u64*)     take((size_t)N * WORDS * sizeof(u64));  // ~4.1 MB
    double*   pssum    = (double*)  take((size_t)N * 4 * sizeof(double));
    int*      pcnt     = (int*)     take((size_t)N * 4 * sizeof(int));
    unsigned* interFull= (unsigned*)take((size_t)N * N * sizeof(unsigned)); // ~1 MB
    unsigned* doneCnt  = (unsigned*)take(sizeof(unsigned));
    (void)ws_size; (void)n_in; (void)out_size;

    k_pack<<<N * 4, 256, 0, stream>>>(preds, packed, pssum, pcnt,
                                      interFull, doneCnt, N, HW);

    const int NT = (N + TPB - 1) / TPB;
    dim3 grid(NT * (NT + 1) / 2, NSPLIT);
    k_inter<<<grid, 256, 0, stream>>>(packed, interFull, doneCnt,
                                      pssum, pcnt, cate, labels,
                                      out, N, WORDS, NT);
}

// Round 7
// 370.784 us; speedup vs baseline: 1.2352x; 1.2352x over previous
//
#include <hip/hip_runtime.h>
#include <cstdint>

typedef unsigned long long u64;

#define THRESH 0.5f
#define SIGMA 2.0f
#define TPB 64      // pair-tile dim (64x64 pairs per tile)
#define NSPLIT 16   // K splits per tile (1024 words / 16 = 64-word chunks)
#define CST 66      // LDS row stride (u64): <=2-way bank aliasing
#define MAXN 512    // tail capacity (N=500)
#define CAP 16      // per-row cached suppressor list (mean ~3; overflow -> rescan)

struct Tail {
    u64 key[MAXN];               // (score_bits<<32)|(~idx): key[a]>key[b] <=> a before b in ref sort
    float score[MAXN];
    float sum[MAXN];
    int label[MAXN];
    float comp[MAXN];
    int cnt[MAXN];
    unsigned short rank[MAXN];
    unsigned short alist[MAXN][CAP];
    float dlist[MAXN][CAP];
    float gred[4];
    float gmin;
    int isLast;
};                               // ~64.5 KB

union InterShared {
    u64 sm[2 * TPB][CST];        // 67,584 B popcount staging
    Tail t;                      // reused by the elected tail block
};

// ---------------------------------------------------------------------------
// K1: 4 blocks per mask. Binarize + bit-pack via 64-lane __ballot (fixed
// pixel<->bit bijection identical for all masks -> popcount(AND) exact).
// Wave covers 4096 contiguous px; 4-deep float4 load pipeline; ballot words
// buffered in wave-private LDS rows, then ONE coalesced 512B store per wave
// (8K wave-stores total vs 128K masked 32B stores before). fp64 partial
// soft-sums per task. Also zero-fills interFull + doneCnt for K2.
// ---------------------------------------------------------------------------
__global__ __launch_bounds__(256) void k_pack(
    const float* __restrict__ preds, u64* __restrict__ packed,
    double* __restrict__ pssum, int* __restrict__ pcnt,
    unsigned* __restrict__ interFull, unsigned* __restrict__ doneCnt,
    int N, int HW)
{
    __shared__ u64 smw[4][64];
    __shared__ double ls[4];
    __shared__ int lc[4];
    const int task = blockIdx.x;
    const int i = task >> 2, sub = task & 3;
    const int seg = HW >> 2;                      // 16384 px per task
    const float* src = preds + (size_t)i * HW + (size_t)sub * seg;
    u64* dst = packed + (size_t)i * (HW >> 6) + (size_t)sub * (seg >> 6);
    const int tid = threadIdx.x;
    const int wave = tid >> 6, lane = tid & 63;

    // zero-init slice of interFull + done counter (used by K2 after boundary)
    {
        const size_t NN = (size_t)N * N;
        const size_t zbase = (size_t)task * 128;
        for (int z = tid; z < 128; z += 256) {
            const size_t idx = zbase + (size_t)z;
            if (idx < NN) interFull[idx] = 0u;
        }
        if (task == 0 && tid == 0) *doneCnt = 0u;
    }

    const float* wsrc = src + (wave << 12);       // wave-contiguous 4096 px
    double ssum = 0.0;
    int cnt = 0;
    for (int k = 0; k < 4; ++k) {
        const int base = (k << 10) + (lane << 2);
        float4 v0 = *reinterpret_cast<const float4*>(wsrc + base);
        float4 v1 = *reinterpret_cast<const float4*>(wsrc + base + 256);
        float4 v2 = *reinterpret_cast<const float4*>(wsrc + base + 512);
        float4 v3 = *reinterpret_cast<const float4*>(wsrc + base + 768);
        #pragma unroll
        for (int q = 0; q < 4; ++q) {
            const float4 v = (q == 0) ? v0 : (q == 1) ? v1 : (q == 2) ? v2 : v3;
            const bool b0 = v.x > THRESH, b1 = v.y > THRESH, b2 = v.z > THRESH, b3 = v.w > THRESH;
            const u64 m0 = __ballot(b0);
            const u64 m1 = __ballot(b1);
            const u64 m2 = __ballot(b2);
            const u64 m3 = __ballot(b3);
            if (lane < 4) {
                const u64 m = (lane == 0) ? m0 : (lane == 1) ? m1 : (lane == 2) ? m2 : m3;
                smw[wave][(k << 4) + (q << 2) + lane] = m;   // wave-private row
            }
            cnt += (int)b0 + (int)b1 + (int)b2 + (int)b3;
            ssum += (b0 ? (double)v.x : 0.0) + (b1 ? (double)v.y : 0.0)
                  + (b2 ? (double)v.z : 0.0) + (b3 ? (double)v.w : 0.0);
        }
    }
    // coalesced store: 64 contiguous words per wave (512 B)
    dst[(wave << 6) + lane] = smw[wave][lane];

    for (int off = 32; off > 0; off >>= 1) {
        ssum += __shfl_down(ssum, off);
        cnt  += __shfl_down(cnt, off);
    }
    if (lane == 0) { ls[wave] = ssum; lc[wave] = cnt; }
    __syncthreads();
    if (tid == 0) {
        pssum[task] = ls[0] + ls[1] + ls[2] + ls[3];
        pcnt[task]  = lc[0] + lc[1] + lc[2] + lc[3];
    }
}

// ---------------------------------------------------------------------------
// K2: pairwise intersections (atomicAdd per-split partials into dense
// interFull) + elected-last-block tail. Tail is restructured into LDS-parallel
// micro-phases so NO phase runs a long divergent global-load loop:
//   A1 (pure LDS): rank + matched-suppressor lists
//   A2: flat parallel fetch of only the listed interFull values (~1.5K loads)
//   A3: comp from cached d's;  B: decay + scatter by rank.
// ---------------------------------------------------------------------------
__global__ __launch_bounds__(256) void k_inter(
    const u64* __restrict__ packed, unsigned* __restrict__ interFull,
    unsigned* __restrict__ doneCnt,
    const double* __restrict__ pssum, const int* __restrict__ pcnt,
    const float* __restrict__ cate, const int* __restrict__ labels,
    float* __restrict__ out, int N, int WORDS, int NT)
{
    __shared__ InterShared sh;
    const int tid = threadIdx.x;

    // ---- popcount phase ----
    {
        int b = blockIdx.x;
        int ti = 0, rowlen = NT;
        while (b >= rowlen) { b -= rowlen; ++ti; --rowlen; }
        const int tj = ti + b;
        const int kwords = WORDS / NSPLIT;
        const int kbase = blockIdx.y * kwords;
        const int a = tid >> 4, bb = tid & 15;

        const int half = kwords >> 1;
        for (int idx = tid; idx < 2 * TPB * half; idx += 256) {
            const int ml = idx / half;
            const int w = (idx - ml * half) << 1;
            const int g = (ml < TPB) ? (ti * TPB + ml) : (tj * TPB + (ml - TPB));
            u64 x0 = 0, x1 = 0;
            if (g < N) {
                const u64* p = packed + (size_t)g * WORDS + kbase + w;
                x0 = p[0];
                x1 = p[1];
            }
            sh.sm[ml][w] = x0;
            sh.sm[ml][w + 1] = x1;
        }
        __syncthreads();

        unsigned acc[4][4] = {};
        #pragma unroll 4
        for (int w = 0; w < kwords; w += 2) {
            u64 pi0[4], pi1[4], pj0[4], pj1[4];
            #pragma unroll
            for (int t = 0; t < 4; ++t) {
                const ulonglong2 q = *reinterpret_cast<const ulonglong2*>(&sh.sm[4 * a + t][w]);
                pi0[t] = q.x; pi1[t] = q.y;
            }
            #pragma unroll
            for (int s = 0; s < 4; ++s) {
                const ulonglong2 q = *reinterpret_cast<const ulonglong2*>(&sh.sm[TPB + bb + 16 * s][w]);
                pj0[s] = q.x; pj1[s] = q.y;
            }
            #pragma unroll
            for (int t = 0; t < 4; ++t)
                #pragma unroll
                for (int s = 0; s < 4; ++s)
                    acc[t][s] += (unsigned)__popcll(pi0[t] & pj0[s])
                               + (unsigned)__popcll(pi1[t] & pj1[s]);
        }
        #pragma unroll
        for (int t = 0; t < 4; ++t)
            #pragma unroll
            for (int s = 0; s < 4; ++s) {
                const int gi = ti * TPB + 4 * a + t;
                const int gj = tj * TPB + bb + 16 * s;
                if (gj < N && gi < gj)
                    atomicAdd(&interFull[(size_t)gi * N + gj], acc[t][s]);
            }
    }

    // ---- last-block election ----
    __syncthreads();
    if (tid == 0) {
        __threadfence();                  // release my atomics
        const unsigned total = gridDim.x * gridDim.y;
        const unsigned prev = atomicAdd(doneCnt, 1u);
        sh.t.isLast = (prev == total - 1u) ? 1 : 0;
    }
    __syncthreads();
    if (!sh.t.isLast) return;
    __threadfence();                      // acquire all blocks' atomics

    // ---- tail ----
    for (int b = tid; b < MAXN; b += 256) { sh.t.key[b] = 0; sh.t.cnt[b] = 0; }
    __syncthreads();
    for (int b = tid; b < N; b += 256) {
        const double S = ((pssum[4*b] + pssum[4*b+1]) + pssum[4*b+2]) + pssum[4*b+3];
        const int C = ((pcnt[4*b] + pcnt[4*b+1]) + pcnt[4*b+2]) + pcnt[4*b+3];
        const float sc = cate[b] * (float)(S / (double)(C > 1 ? C : 1));
        sh.t.score[b] = sc;
        sh.t.sum[b] = (float)C;
        sh.t.label[b] = labels[b];
        sh.t.key[b] = ((u64)__float_as_uint(sc) << 32) | (u64)(0xFFFFFFFFu - (unsigned)b);
    }
    __syncthreads();

    // A1: rank + matched-suppressor lists (pure LDS; broadcast inner reads)
    for (int b = tid; b < N; b += 256) {
        const u64 kb = sh.t.key[b];
        const int lb = sh.t.label[b];
        int r = 0;
        for (int a2 = 0; a2 < N; ++a2) {
            if (sh.t.key[a2] > kb) {
                ++r;
                if (sh.t.label[a2] == lb) {
                    const int slot = atomicAdd(&sh.t.cnt[b], 1);
                    if (slot < CAP) sh.t.alist[b][slot] = (unsigned short)a2;
                }
            }
        }
        sh.t.rank[b] = (unsigned short)r;
    }
    __syncthreads();

    // A2: fetch only the listed intersections (independent parallel loads)
    for (int b = tid; b < N; b += 256) {
        const float sub = sh.t.sum[b];
        const int c = min(sh.t.cnt[b], CAP);
        for (int s = 0; s < c; ++s) {
            const int a2 = sh.t.alist[b][s];
            const int lo = a2 < b ? a2 : b, hi = a2 < b ? b : a2;
            const unsigned iv = __hip_atomic_load(&interFull[(size_t)lo * N + hi],
                __ATOMIC_RELAXED, __HIP_MEMORY_SCOPE_AGENT);
            const float inter = (float)iv;
            const float un = sh.t.sum[a2] + sub - inter;
            sh.t.dlist[b][s] = inter / fmaxf(un, 1.0f);
        }
    }
    __syncthreads();

    // A3: comp (cached; overflow rows rescan with loads — rare)
    for (int b = tid; b < N; b += 256) {
        const int cc = sh.t.cnt[b];
        float cmax = 0.0f;
        if (cc <= CAP) {
            for (int s = 0; s < cc; ++s) cmax = fmaxf(cmax, sh.t.dlist[b][s]);
        } else {
            const u64 kb = sh.t.key[b];
            const int lb = sh.t.label[b];
            const float sub = sh.t.sum[b];
            for (int a2 = 0; a2 < N; ++a2) {
                if (sh.t.key[a2] > kb && sh.t.label[a2] == lb) {
                    const int lo = a2 < b ? a2 : b, hi = a2 < b ? b : a2;
                    const unsigned iv = __hip_atomic_load(&interFull[(size_t)lo * N + hi],
                        __ATOMIC_RELAXED, __HIP_MEMORY_SCOPE_AGENT);
                    const float inter = (float)iv;
                    const float un = sh.t.sum[a2] + sub - inter;
                    cmax = fmaxf(cmax, inter / fmaxf(un, 1.0f));
                }
            }
        }
        sh.t.comp[b] = cmax;
    }
    __syncthreads();

    // global min of comp (all d=0 columns contribute max_a(-comp[a]^2) = -gmin^2)
    {
        const int wave = tid >> 6, lane = tid & 63;
        float gm = 3.0e38f;
        for (int b = tid; b < N; b += 256) gm = fminf(gm, sh.t.comp[b]);
        for (int off = 32; off > 0; off >>= 1) gm = fminf(gm, __shfl_down(gm, off));
        if (lane == 0) sh.t.gred[wave] = gm;
        __syncthreads();
        if (tid == 0)
            sh.t.gmin = fminf(fminf(sh.t.gred[0], sh.t.gred[1]),
                              fminf(sh.t.gred[2], sh.t.gred[3]));
        __syncthreads();
    }
    const float gmin = sh.t.gmin;

    // B: decay + scatter by rank (ranks are a permutation; ties impossible)
    for (int b = tid; b < N; b += 256) {
        float m = -(gmin * gmin);
        const int cc = sh.t.cnt[b];
        if (cc <= CAP) {
            for (int s = 0; s < cc; ++s) {
                const int a2 = sh.t.alist[b][s];
                const float d = sh.t.dlist[b][s];
                const float ca = sh.t.comp[a2];
                m = fmaxf(m, d * d - ca * ca);
            }
        } else {
            const u64 kb = sh.t.key[b];
            const int lb = sh.t.label[b];
            const float sub = sh.t.sum[b];
            for (int a2 = 0; a2 < N; ++a2) {
                if (sh.t.key[a2] > kb && sh.t.label[a2] == lb) {
                    const int lo = a2 < b ? a2 : b, hi = a2 < b ? b : a2;
                    const unsigned iv = __hip_atomic_load(&interFull[(size_t)lo * N + hi],
                        __ATOMIC_RELAXED, __HIP_MEMORY_SCOPE_AGENT);
                    const float inter = (float)iv;
                    const float un = sh.t.sum[a2] + sub - inter;
                    const float d = inter / fmaxf(un, 1.0f);
                    const float ca = sh.t.comp[a2];
                    m = fmaxf(m, d * d - ca * ca);
                }
            }
        }
        out[sh.t.rank[b]] = sh.t.score[b] * expf(-SIGMA * m);
    }
}

extern "C" void kernel_launch(void* const* d_in, const int* in_sizes, int n_in,
                              void* d_out, int out_size, void* d_ws, size_t ws_size,
                              hipStream_t stream)
{
    const float* preds  = (const float*)d_in[0];
    const float* cate   = (const float*)d_in[1];
    const int*   labels = (const int*)d_in[2];
    float* out = (float*)d_out;

    const int N = in_sizes[1];
    const int HW = in_sizes[0] / N;
    const int WORDS = HW >> 6;

    char* ws = (char*)d_ws;
    size_t off = 0;
    auto take = [&](size_t bytes) -> void* {
        void* p = ws + off;
        off = (off + bytes + 255) & ~(size_t)255;
        return p;
    };
    u64*      packed    = (u64*)     take((size_t)N * WORDS * sizeof(u64));  // ~4.1 MB
    double*   pssum     = (double*)  take((size_t)N * 4 * sizeof(double));
    int*      pcnt      = (int*)     take((size_t)N * 4 * sizeof(int));
    unsigned* interFull = (unsigned*)take((size_t)N * N * sizeof(unsigned)); // ~1 MB
    unsigned* doneCnt   = (unsigned*)take(sizeof(unsigned));
    (void)ws_size; (void)n_in; (void)out_size;

    k_pack<<<N * 4, 256, 0, stream>>>(preds, packed, pssum, pcnt,
                                      interFull, doneCnt, N, HW);

    const int NT = (N + TPB - 1) / TPB;
    dim3 grid(NT * (NT + 1) / 2, NSPLIT);
    k_inter<<<grid, 256, 0, stream>>>(packed, interFull, doneCnt,
                                      pssum, pcnt, cate, labels,
                                      out, N, WORDS, NT);
}